// Round 10
// baseline (228.995 us; speedup 1.0000x reference)
//
#include <hip/hip_runtime.h>
#include <hip/hip_bf16.h>
#include <stdint.h>

#define D_DIM 128
#define L_REL 32
#define ST_LDW 66     // dword stride for agg self tile (264B rows)
#define CPB 4

typedef __attribute__((ext_vector_type(8))) short short8;   // 8 bf16 = 4 VGPR
typedef __attribute__((ext_vector_type(4))) float f32x4;    // MFMA accumulator

__device__ __forceinline__ unsigned short f2bf(float f) {
    union { float f; unsigned u; } v; v.f = f;
    unsigned r = v.u + 0x7FFFu + ((v.u >> 16) & 1u);   // round-to-nearest-even
    return (unsigned short)(r >> 16);
}
__device__ __forceinline__ float bf_lo(unsigned m) { return __uint_as_float(m << 16); }
__device__ __forceinline__ float bf_hi(unsigned m) { return __uint_as_float(m & 0xffff0000u); }

// B-operand fragment: lane holds W[k][c] for c = tile*16 + (lane&15),
// k = kk*32 + (lane>>4)*8 + j (j contiguous).
__device__ __forceinline__ void load_wfrag(const float* __restrict__ Wr,
                                           int w, int l15, int lq,
                                           short8 wf[2][4]) {
#pragma unroll
    for (int n = 0; n < 2; ++n) {
        int c = (w * 2 + n) * 16 + l15;
#pragma unroll
        for (int kk = 0; kk < 4; ++kk) {
            int kb = kk * 32 + lq * 8;
            short8 f;
#pragma unroll
            for (int j = 0; j < 8; ++j)
                f[j] = (short)f2bf(Wr[(size_t)(kb + j) * D_DIM + c]);
            wf[n][kk] = f;
        }
    }
}

// 64x128 (rows x k, bf16, XOR-swizzled) LDS tile  @  W(128x128) -> acc 64x128
__device__ __forceinline__ void mfma_tile(const unsigned short* xs,
                                          const short8 wf[2][4],
                                          int l15, int lq, f32x4 acc[4][2]) {
#pragma unroll
    for (int kk = 0; kk < 4; ++kk) {
        short8 a[4];
#pragma unroll
        for (int m = 0; m < 4; ++m) {
            int row = m * 16 + l15;
            unsigned byte = ((unsigned)(row * 256 + (kk * 32 + lq * 8) * 2))
                          ^ (((unsigned)(row & 7)) << 4);
            a[m] = *reinterpret_cast<const short8*>(
                       reinterpret_cast<const char*>(xs) + byte);
        }
#pragma unroll
        for (int m = 0; m < 4; ++m)
#pragma unroll
            for (int n = 0; n < 2; ++n)
                acc[m][n] = __builtin_amdgcn_mfma_f32_16x16x32_bf16(
                                a[m], wf[n][kk], acc[m][n], 0, 0, 0);
    }
}

// ===================== combined CSR build (deg = in-deg fwd+rev) ===========
__global__ void hist_kernel(const int* __restrict__ dep, const int* __restrict__ gov,
                            int* __restrict__ deg, int E) {
    int i = blockIdx.x * blockDim.x + threadIdx.x;
    int stride = gridDim.x * blockDim.x;
    for (; i < E; i += stride) {
        atomicAdd(&deg[dep[i]], 1);
        atomicAdd(&deg[gov[i]], 1);
    }
}

__global__ __launch_bounds__(256) void scanA_kernel(const int* __restrict__ deg,
                                                    int* __restrict__ off,
                                                    int* __restrict__ partials) {
    __shared__ int ls[256];
    const int tid = threadIdx.x;
    const int gi = blockIdx.x * 256 + tid;
    int4 v = ((const int4*)deg)[gi];
    int s = v.x + v.y + v.z + v.w;
    ls[tid] = s;
    __syncthreads();
    for (int o = 1; o < 256; o <<= 1) {
        int t = (tid >= o) ? ls[tid - o] : 0;
        __syncthreads();
        ls[tid] += t;
        __syncthreads();
    }
    int e0 = ls[tid] - s;
    int4 e; e.x = e0; e.y = e0 + v.x; e.z = e.y + v.y; e.w = e.z + v.z;
    ((int4*)off)[gi] = e;
    if (tid == 255) partials[blockIdx.x] = ls[255];
}

__global__ __launch_bounds__(256) void scanB_kernel(int* __restrict__ partials) {
    __shared__ int ls[256];
    const int tid = threadIdx.x;
    int v = partials[tid];
    ls[tid] = v;
    __syncthreads();
    for (int o = 1; o < 256; o <<= 1) {
        int t = (tid >= o) ? ls[tid - o] : 0;
        __syncthreads();
        ls[tid] += t;
        __syncthreads();
    }
    partials[tid] = ls[tid] - v;   // exclusive
}

__global__ __launch_bounds__(256) void scanC_kernel(int* __restrict__ off,
                                                    int* __restrict__ cur,
                                                    const int* __restrict__ partials) {
    const int p = partials[blockIdx.x];
    const int gi = blockIdx.x * 256 + threadIdx.x;
    int4 v = ((int4*)off)[gi];
    v.x += p; v.y += p; v.z += p; v.w += p;
    ((int4*)off)[gi] = v;
    ((int4*)cur)[gi] = v;
}

// ====================== messages -> dst-sorted bf16 buffer ==================
// msg row layout is MFMA-native: dword j holds cols (32*(j>>4)+(j&15), +16).
// Store straight from acc registers (no LDS transpose, no 2nd barrier).
// xs ping-pong + pos ping-pong -> ONE barrier per chunk.
__global__ __launch_bounds__(256) void msg_kernel(const float* __restrict__ x,
                                                  const float* __restrict__ W,
                                                  const float* __restrict__ b,
                                                  const int* __restrict__ dep,
                                                  const int* __restrict__ gov,
                                                  int* __restrict__ cur,
                                                  unsigned* __restrict__ msg,
                                                  int eg, int blocksPerRel) {
    __shared__ __align__(16) unsigned short xs[2][64 * 128];   // 2 x 16 KB
    __shared__ int sidx[CPB][64];
    __shared__ int didx[CPB][64];
    __shared__ int pos[2][64];

    const int tid = threadIdx.x;
    const int lane = tid & 63, w = tid >> 6;
    const int l15 = lane & 15, lq = lane >> 4;

    const int bid = blockIdx.x;
    const int vr = bid / blocksPerRel;
    const int blk = bid % blocksPerRel;
    const int r = vr & 31;
    const bool fwd = (vr < 32);
    const int* __restrict__ srcI = fwd ? gov : dep;
    const int* __restrict__ dstI = fwd ? dep : gov;

    const int ebase0 = r * eg + blk * CPB * 64;
    {
        int c = tid >> 6, t = tid & 63;   // 256 threads cover 4x64
        sidx[c][t] = srcI[ebase0 + c * 64 + t];
        didx[c][t] = dstI[ebase0 + c * 64 + t];
    }

    short8 wf[2][4];
    load_wfrag(W + (size_t)(2 + vr) * D_DIM * D_DIM, w, l15, lq, wf);
    float bias[2];
#pragma unroll
    for (int n = 0; n < 2; ++n)
        bias[n] = b[(size_t)(2 + vr) * D_DIM + (w * 2 + n) * 16 + l15];

    const int srow = tid >> 5;            // staging: 32 thr/row, 16B each
    const int sf4  = tid & 31;
    __syncthreads();                      // sidx/didx visible

    // prologue: stage chunk 0 + its pos
    {
        float4 st0[8];
#pragma unroll
        for (int it = 0; it < 8; ++it) {
            int row = it * 8 + srow;
            st0[it] = *reinterpret_cast<const float4*>(
                          x + (size_t)sidx[0][row] * D_DIM + sf4 * 4);
        }
#pragma unroll
        for (int it = 0; it < 8; ++it) {
            int row = it * 8 + srow;
            unsigned lo = (unsigned)f2bf(st0[it].x) | ((unsigned)f2bf(st0[it].y) << 16);
            unsigned hi = (unsigned)f2bf(st0[it].z) | ((unsigned)f2bf(st0[it].w) << 16);
            unsigned byte = ((unsigned)(row * 256 + sf4 * 8))
                          ^ (((unsigned)(row & 7)) << 4);
            *reinterpret_cast<uint2*>(reinterpret_cast<char*>(xs[0]) + byte) =
                make_uint2(lo, hi);
        }
        if (tid < 64) pos[0][tid] = atomicAdd(&cur[didx[0][tid]], 1);
    }
    __syncthreads();

    for (int ch = 0; ch < CPB; ++ch) {
        const int cb = ch & 1;

        // issue next chunk's gather early (hides under MFMA + stores)
        float4 nx[8];
        if (ch + 1 < CPB) {
#pragma unroll
            for (int it = 0; it < 8; ++it) {
                int row = it * 8 + srow;
                nx[it] = *reinterpret_cast<const float4*>(
                             x + (size_t)sidx[ch + 1][row] * D_DIM + sf4 * 4);
            }
        }

        f32x4 acc[4][2];
#pragma unroll
        for (int m = 0; m < 4; ++m)
#pragma unroll
            for (int n = 0; n < 2; ++n) acc[m][n] = (f32x4){0.f, 0.f, 0.f, 0.f};
        mfma_tile(xs[cb], wf, l15, lq, acc);

        // store straight from registers: row = m*16+lq*4+reg,
        // dword index = w*16+l15 -> cols (32w+l15, 32w+16+l15)
#pragma unroll
        for (int m = 0; m < 4; ++m)
#pragma unroll
            for (int reg = 0; reg < 4; ++reg) {
                int row = m * 16 + lq * 4 + reg;
                unsigned dw = (unsigned)f2bf(acc[m][0][reg] + bias[0])
                            | ((unsigned)f2bf(acc[m][1][reg] + bias[1]) << 16);
                msg[(size_t)pos[cb][row] * 64 + w * 16 + l15] = dw;
            }

        if (ch + 1 < CPB) {
            // write next chunk into the other xs buffer + its pos
#pragma unroll
            for (int it = 0; it < 8; ++it) {
                int row = it * 8 + srow;
                unsigned lo = (unsigned)f2bf(nx[it].x) | ((unsigned)f2bf(nx[it].y) << 16);
                unsigned hi = (unsigned)f2bf(nx[it].z) | ((unsigned)f2bf(nx[it].w) << 16);
                unsigned byte = ((unsigned)(row * 256 + sf4 * 8))
                              ^ (((unsigned)(row & 7)) << 4);
                *reinterpret_cast<uint2*>(reinterpret_cast<char*>(xs[cb ^ 1]) + byte) =
                    make_uint2(lo, hi);
            }
            if (tid < 64) pos[cb ^ 1][tid] = atomicAdd(&cur[didx[ch + 1][tid]], 1);
            __syncthreads();   // xs[cb^1] + pos[cb^1] visible for next iter
        }
    }
}

// ====== fused: self-GEMM + monotone streaming msg reduce + bias + ReLU =====
// Self tile stored as packed bf16 dwords with the SAME lane->col mapping as
// msg rows: dword j of row holds cols (32*(j>>4)+(j&15), +16).
__global__ __launch_bounds__(256) void agg_kernel(const float* __restrict__ x,
                                                  const float* __restrict__ W,
                                                  const float* __restrict__ b,
                                                  const int* __restrict__ off,
                                                  const int* __restrict__ deg,
                                                  const unsigned* __restrict__ msg,
                                                  float* __restrict__ out) {
    // union: xs (16KB) -> self tile dwords (64 x ST_LDW, 16.9KB)
    __shared__ __align__(16) char smem[64 * ST_LDW * 4];
    unsigned short* xs = (unsigned short*)smem;
    unsigned* stu = (unsigned*)smem;
    __shared__ int offs[64 + 1];   // offs[64] = end of block's row range

    const int tid = threadIdx.x;
    const int lane = tid & 63, w = tid >> 6;
    const int l15 = lane & 15, lq = lane >> 4;
    const int base = blockIdx.x * 64;

    if (tid < 64) offs[tid] = off[base + tid];
    if (tid == 64) offs[64] = off[base + 63] + deg[base + 63];

    short8 wf[2][4];
    load_wfrag(W, w, l15, lq, wf);          // W[SELF]
    float bias[2];
#pragma unroll
    for (int n = 0; n < 2; ++n) bias[n] = b[(w * 2 + n) * 16 + l15];

    // stage 64 consecutive node rows
#pragma unroll
    for (int it = 0; it < 8; ++it) {
        int flat = it * 256 + tid;
        int row = flat >> 5, f4 = flat & 31;
        float4 v = *reinterpret_cast<const float4*>(
                       x + (size_t)(base + row) * D_DIM + f4 * 4);
        unsigned lo = (unsigned)f2bf(v.x) | ((unsigned)f2bf(v.y) << 16);
        unsigned hi = (unsigned)f2bf(v.z) | ((unsigned)f2bf(v.w) << 16);
        unsigned byte = ((unsigned)(row * 256 + f4 * 8))
                      ^ (((unsigned)(row & 7)) << 4);
        *reinterpret_cast<uint2*>(reinterpret_cast<char*>(xs) + byte) =
            make_uint2(lo, hi);
    }
    __syncthreads();

    f32x4 acc[4][2];
#pragma unroll
    for (int m = 0; m < 4; ++m)
#pragma unroll
        for (int n = 0; n < 2; ++n) acc[m][n] = (f32x4){0.f, 0.f, 0.f, 0.f};
    mfma_tile(xs, wf, l15, lq, acc);
    __syncthreads();   // xs consumed; LDS becomes packed self tile

    // seed self tile (+bias), packed dwords, msg-native mapping
#pragma unroll
    for (int m = 0; m < 4; ++m)
#pragma unroll
        for (int reg = 0; reg < 4; ++reg) {
            int row = m * 16 + lq * 4 + reg;
            unsigned dw = (unsigned)f2bf(acc[m][0][reg] + bias[0])
                        | ((unsigned)f2bf(acc[m][1][reg] + bias[1]) << 16);
            stu[row * ST_LDW + w * 16 + l15] = dw;
        }
    __syncthreads();

    // ---- monotone stream over this wave's contiguous rows ----
    const int nfirst = w * 16;
    const int c0 = lq * 32 + l15;    // lane's lo column; hi = c0+16
    int ci = 0;                      // node cursor within wave's 16
    float2 accm = make_float2(0.f, 0.f);

#define FLUSH_NODE()                                                          \
    do {                                                                      \
        const unsigned sv = stu[(nfirst + ci) * ST_LDW + lane];               \
        float* orow = out + (size_t)(base + nfirst + ci) * D_DIM;             \
        orow[c0]      = fmaxf(bf_lo(sv) + accm.x, 0.f);                       \
        orow[c0 + 16] = fmaxf(bf_hi(sv) + accm.y, 0.f);                       \
        accm.x = 0.f; accm.y = 0.f;                                           \
        ++ci;                                                                 \
    } while (0)

    const int s0 = offs[nfirst];
    const int s1 = offs[nfirst + 16];
    int nb = offs[nfirst + 1];
    int j = s0;
    const unsigned* mp = msg + (size_t)j * 64 + lane;

    // 16 rows in flight
    for (; j + 16 <= s1; j += 16, mp += 1024) {
        unsigned v[16];
#pragma unroll
        for (int k = 0; k < 16; ++k) v[k] = mp[k * 64];
#pragma unroll
        for (int k = 0; k < 16; ++k) {
            int jj = j + k;
            while (jj >= nb) { FLUSH_NODE(); nb = offs[nfirst + ci + 1]; }
            accm.x += bf_lo(v[k]); accm.y += bf_hi(v[k]);
        }
    }
    for (; j < s1; ++j, mp += 64) {
        unsigned v = mp[0];
        while (j >= nb) { FLUSH_NODE(); nb = offs[nfirst + ci + 1]; }
        accm.x += bf_lo(v); accm.y += bf_hi(v);
    }
    // drain remaining nodes (incl. zero-degree tail)
    while (ci < 16) FLUSH_NODE();
#undef FLUSH_NODE
}

// ===================== fallback (R2 atomic path) ===========================
__global__ __launch_bounds__(256) void self_kernel(const float* __restrict__ x,
                                                   const float* __restrict__ W,
                                                   const float* __restrict__ b,
                                                   float* __restrict__ out) {
    __shared__ unsigned short xs[64 * D_DIM];
    const int tid = threadIdx.x;
    const int lane = tid & 63, w = tid >> 6;
    const int l15 = lane & 15, lq = lane >> 4;
    short8 wf[2][4];
    load_wfrag(W, w, l15, lq, wf);
    float bias[2];
#pragma unroll
    for (int n = 0; n < 2; ++n) bias[n] = b[(w * 2 + n) * 16 + l15];
    const int rbase = blockIdx.x * 64;
#pragma unroll
    for (int it = 0; it < 8; ++it) {
        int flat = it * 256 + tid;
        int row = flat >> 5, f4 = flat & 31;
        float4 v = *reinterpret_cast<const float4*>(
                       x + (size_t)(rbase + row) * D_DIM + f4 * 4);
        unsigned lo = (unsigned)f2bf(v.x) | ((unsigned)f2bf(v.y) << 16);
        unsigned hi = (unsigned)f2bf(v.z) | ((unsigned)f2bf(v.w) << 16);
        unsigned byte = ((unsigned)(row * 256 + f4 * 8))
                      ^ (((unsigned)(row & 7)) << 4);
        *reinterpret_cast<uint2*>(reinterpret_cast<char*>(xs) + byte) =
            make_uint2(lo, hi);
    }
    __syncthreads();
    f32x4 acc[4][2];
#pragma unroll
    for (int m = 0; m < 4; ++m)
#pragma unroll
        for (int n = 0; n < 2; ++n) acc[m][n] = (f32x4){0.f, 0.f, 0.f, 0.f};
    mfma_tile(xs, wf, l15, lq, acc);
#pragma unroll
    for (int m = 0; m < 4; ++m)
#pragma unroll
        for (int reg = 0; reg < 4; ++reg) {
            int row = rbase + m * 16 + lq * 4 + reg;
#pragma unroll
            for (int n = 0; n < 2; ++n) {
                int c = (w * 2 + n) * 16 + l15;
                out[(size_t)row * D_DIM + c] = acc[m][n][reg] + bias[n];
            }
        }
}

__global__ __launch_bounds__(256) void edge_kernel(const float* __restrict__ x,
                                                   const float* __restrict__ W,
                                                   const float* __restrict__ b,
                                                   const int* __restrict__ dep,
                                                   const int* __restrict__ gov,
                                                   float* __restrict__ out,
                                                   int eg, int blocksPerRel) {
    __shared__ unsigned short xs[64 * D_DIM];
    __shared__ int sidx[CPB][64];
    __shared__ int didx[CPB][64];
    const int tid = threadIdx.x;
    const int lane = tid & 63, w = tid >> 6;
    const int l15 = lane & 15, lq = lane >> 4;
    const int bid = blockIdx.x;
    const int vr = bid / blocksPerRel;
    const int blk = bid % blocksPerRel;
    const int r = vr & 31;
    const bool fwd = (vr < 32);
    const int* __restrict__ srcI = fwd ? gov : dep;
    const int* __restrict__ dstI = fwd ? dep : gov;
    const int ebase0 = r * eg + blk * CPB * 64;
    {
        int c = tid >> 6, t = tid & 63;
        sidx[c][t] = srcI[ebase0 + c * 64 + t];
        didx[c][t] = dstI[ebase0 + c * 64 + t];
    }
    short8 wf[2][4];
    load_wfrag(W + (size_t)(2 + vr) * D_DIM * D_DIM, w, l15, lq, wf);
    float bias[2];
#pragma unroll
    for (int n = 0; n < 2; ++n)
        bias[n] = b[(size_t)(2 + vr) * D_DIM + (w * 2 + n) * 16 + l15];
    __syncthreads();
#pragma unroll
    for (int ch = 0; ch < CPB; ++ch) {
#pragma unroll
        for (int it = 0; it < 8; ++it) {
            int flat = it * 256 + tid;
            int row = flat >> 5, f4 = flat & 31;
            float4 v = *reinterpret_cast<const float4*>(
                           x + (size_t)sidx[ch][row] * D_DIM + f4 * 4);
            unsigned lo = (unsigned)f2bf(v.x) | ((unsigned)f2bf(v.y) << 16);
            unsigned hi = (unsigned)f2bf(v.z) | ((unsigned)f2bf(v.w) << 16);
            unsigned byte = ((unsigned)(row * 256 + f4 * 8))
                          ^ (((unsigned)(row & 7)) << 4);
            *reinterpret_cast<uint2*>(reinterpret_cast<char*>(xs) + byte) =
                make_uint2(lo, hi);
        }
        __syncthreads();
        f32x4 acc[4][2];
#pragma unroll
        for (int m = 0; m < 4; ++m)
#pragma unroll
            for (int n = 0; n < 2; ++n) acc[m][n] = (f32x4){0.f, 0.f, 0.f, 0.f};
        mfma_tile(xs, wf, l15, lq, acc);
#pragma unroll
        for (int m = 0; m < 4; ++m)
#pragma unroll
            for (int reg = 0; reg < 4; ++reg) {
                int erow = m * 16 + lq * 4 + reg;
                int dst = didx[ch][erow];
#pragma unroll
                for (int n = 0; n < 2; ++n) {
                    int c = (w * 2 + n) * 16 + l15;
                    unsafeAtomicAdd(&out[(size_t)dst * D_DIM + c],
                                    acc[m][n][reg] + bias[n]);
                }
            }
        __syncthreads();
    }
}

__global__ void relu_kernel(float* __restrict__ o, int n4) {
    int i = blockIdx.x * blockDim.x + threadIdx.x;
    int stride = gridDim.x * blockDim.x;
    float4* p = reinterpret_cast<float4*>(o);
    for (; i < n4; i += stride) {
        float4 v = p[i];
        v.x = fmaxf(v.x, 0.f); v.y = fmaxf(v.y, 0.f);
        v.z = fmaxf(v.z, 0.f); v.w = fmaxf(v.w, 0.f);
        p[i] = v;
    }
}

// ===========================================================================
extern "C" void kernel_launch(void* const* d_in, const int* in_sizes, int n_in,
                              void* d_out, int out_size, void* d_ws, size_t ws_size,
                              hipStream_t stream) {
    const float* x   = (const float*)d_in[0];
    const float* W   = (const float*)d_in[1];
    const float* b   = (const float*)d_in[2];
    const int*   dep = (const int*)d_in[3];
    const int*   gov = (const int*)d_in[4];
    float* out = (float*)d_out;

    const int N  = in_sizes[0] / D_DIM;   // 262144
    const int E  = in_sizes[3];           // 262144
    const int eg = E / L_REL;             // 8192

    const size_t msgBytes = (size_t)2 * E * 64 * sizeof(unsigned);  // 134.2 MB
    const size_t need = msgBytes + (size_t)(3 * N + 256) * 4 + 4096;

    const int blocksPerRel = eg / 64 / CPB;   // 32

    if (ws_size >= need) {
        char* basep = (char*)d_ws;
        unsigned* msg = (unsigned*)basep;
        int* deg = (int*)(basep + msgBytes);   // [N]
        int* off = deg + (size_t)N;            // [N]
        int* cur = off + (size_t)N;            // [N]
        int* partials = cur + (size_t)N;       // [256]

        hipMemsetAsync(deg, 0, (size_t)N * sizeof(int), stream);
        hist_kernel<<<512, 256, 0, stream>>>(dep, gov, deg, E);
        scanA_kernel<<<N / 1024, 256, 0, stream>>>(deg, off, partials);
        scanB_kernel<<<1, 256, 0, stream>>>(partials);
        scanC_kernel<<<N / 1024, 256, 0, stream>>>(off, cur, partials);

        msg_kernel<<<64 * blocksPerRel, 256, 0, stream>>>(x, W, b, dep, gov,
                                                          cur, msg, eg,
                                                          blocksPerRel);
        agg_kernel<<<N / 64, 256, 0, stream>>>(x, W, b, off, deg, msg, out);
    } else {
        // fallback: atomic scatter path
        self_kernel<<<N / 64, 256, 0, stream>>>(x, W, b, out);
        edge_kernel<<<64 * blocksPerRel, 256, 0, stream>>>(x, W, b, dep, gov, out,
                                                           eg, blocksPerRel);
        relu_kernel<<<2048, 256, 0, stream>>>(out, out_size / 4);
    }
}

// Round 11
// 204.958 us; speedup vs baseline: 1.1173x; 1.1173x over previous
//
#include <hip/hip_runtime.h>
#include <hip/hip_bf16.h>
#include <stdint.h>

#define D_DIM 128
#define L_REL 32
#define MSG_LDW 132   // ushort stride, bf16 tiles (264B rows)
#define CPB 8

typedef __attribute__((ext_vector_type(8))) short short8;   // 8 bf16 = 4 VGPR
typedef __attribute__((ext_vector_type(4))) float f32x4;    // MFMA accumulator

__device__ __forceinline__ unsigned short f2bf(float f) {
    union { float f; unsigned u; } v; v.f = f;
    unsigned r = v.u + 0x7FFFu + ((v.u >> 16) & 1u);   // round-to-nearest-even
    return (unsigned short)(r >> 16);
}
__device__ __forceinline__ float bf_lo(unsigned m) { return __uint_as_float(m << 16); }
__device__ __forceinline__ float bf_hi(unsigned m) { return __uint_as_float(m & 0xffff0000u); }

// B-operand fragment: lane holds W[k][c] for c = tile*16 + (lane&15),
// k = kk*32 + (lane>>4)*8 + j (j contiguous).
__device__ __forceinline__ void load_wfrag(const float* __restrict__ Wr,
                                           int w, int l15, int lq,
                                           short8 wf[2][4]) {
#pragma unroll
    for (int n = 0; n < 2; ++n) {
        int c = (w * 2 + n) * 16 + l15;
#pragma unroll
        for (int kk = 0; kk < 4; ++kk) {
            int kb = kk * 32 + lq * 8;
            short8 f;
#pragma unroll
            for (int j = 0; j < 8; ++j)
                f[j] = (short)f2bf(Wr[(size_t)(kb + j) * D_DIM + c]);
            wf[n][kk] = f;
        }
    }
}

// 64x128 (rows x k, bf16, XOR-swizzled) LDS tile  @  W(128x128) -> acc 64x128
__device__ __forceinline__ void mfma_tile(const unsigned short* xs,
                                          const short8 wf[2][4],
                                          int l15, int lq, f32x4 acc[4][2]) {
#pragma unroll
    for (int kk = 0; kk < 4; ++kk) {
        short8 a[4];
#pragma unroll
        for (int m = 0; m < 4; ++m) {
            int row = m * 16 + l15;
            unsigned byte = ((unsigned)(row * 256 + (kk * 32 + lq * 8) * 2))
                          ^ (((unsigned)(row & 7)) << 4);
            a[m] = *reinterpret_cast<const short8*>(
                       reinterpret_cast<const char*>(xs) + byte);
        }
#pragma unroll
        for (int m = 0; m < 4; ++m)
#pragma unroll
            for (int n = 0; n < 2; ++n)
                acc[m][n] = __builtin_amdgcn_mfma_f32_16x16x32_bf16(
                                a[m], wf[n][kk], acc[m][n], 0, 0, 0);
    }
}

// ===================== combined CSR build (deg = in-deg fwd+rev) ===========
__global__ void hist_kernel(const int* __restrict__ dep, const int* __restrict__ gov,
                            int* __restrict__ deg, int E) {
    int i = blockIdx.x * blockDim.x + threadIdx.x;
    int stride = gridDim.x * blockDim.x;
    for (; i < E; i += stride) {
        atomicAdd(&deg[dep[i]], 1);
        atomicAdd(&deg[gov[i]], 1);
    }
}

__global__ __launch_bounds__(256) void scanA_kernel(const int* __restrict__ deg,
                                                    int* __restrict__ off,
                                                    int* __restrict__ partials) {
    __shared__ int ls[256];
    const int tid = threadIdx.x;
    const int gi = blockIdx.x * 256 + tid;
    int4 v = ((const int4*)deg)[gi];
    int s = v.x + v.y + v.z + v.w;
    ls[tid] = s;
    __syncthreads();
    for (int o = 1; o < 256; o <<= 1) {
        int t = (tid >= o) ? ls[tid - o] : 0;
        __syncthreads();
        ls[tid] += t;
        __syncthreads();
    }
    int e0 = ls[tid] - s;
    int4 e; e.x = e0; e.y = e0 + v.x; e.z = e.y + v.y; e.w = e.z + v.z;
    ((int4*)off)[gi] = e;
    if (tid == 255) partials[blockIdx.x] = ls[255];
}

__global__ __launch_bounds__(256) void scanB_kernel(int* __restrict__ partials) {
    __shared__ int ls[256];
    const int tid = threadIdx.x;
    int v = partials[tid];
    ls[tid] = v;
    __syncthreads();
    for (int o = 1; o < 256; o <<= 1) {
        int t = (tid >= o) ? ls[tid - o] : 0;
        __syncthreads();
        ls[tid] += t;
        __syncthreads();
    }
    partials[tid] = ls[tid] - v;   // exclusive
}

__global__ __launch_bounds__(256) void scanC_kernel(int* __restrict__ off,
                                                    int* __restrict__ cur,
                                                    const int* __restrict__ partials) {
    const int p = partials[blockIdx.x];
    const int gi = blockIdx.x * 256 + threadIdx.x;
    int4 v = ((int4*)off)[gi];
    v.x += p; v.y += p; v.z += p; v.w += p;
    ((int4*)off)[gi] = v;
    ((int4*)cur)[gi] = v;
}

// ====================== messages -> dst-sorted bf16 buffer ==================
// R9 structure (best known): reg-prefetch next chunk during MFMA; tr separate
// from xs; CPB=8 so W-fragment setup is amortized over 512 edges and the
// 1024-block grid is exactly co-resident (4 blocks/CU).
__global__ __launch_bounds__(256) void msg_kernel(const float* __restrict__ x,
                                                  const float* __restrict__ W,
                                                  const float* __restrict__ b,
                                                  const int* __restrict__ dep,
                                                  const int* __restrict__ gov,
                                                  int* __restrict__ cur,
                                                  unsigned* __restrict__ msg,
                                                  int eg, int blocksPerRel) {
    __shared__ __align__(16) unsigned short xs[64 * 128];      // 16 KB, swizzled
    __shared__ __align__(16) unsigned short tr[64 * MSG_LDW];  // 16.9 KB
    __shared__ int sidx[CPB][64];
    __shared__ int didx[CPB][64];
    __shared__ int pos[64];

    const int tid = threadIdx.x;
    const int lane = tid & 63, w = tid >> 6;
    const int l15 = lane & 15, lq = lane >> 4;

    const int bid = blockIdx.x;
    const int vr = bid / blocksPerRel;
    const int blk = bid % blocksPerRel;
    const int r = vr & 31;
    const bool fwd = (vr < 32);
    const int* __restrict__ srcI = fwd ? gov : dep;
    const int* __restrict__ dstI = fwd ? dep : gov;

    const int ebase0 = r * eg + blk * CPB * 64;
#pragma unroll
    for (int c2 = 0; c2 < CPB / 4; ++c2) {
        int c = c2 * 4 + (tid >> 6), t = tid & 63;   // 256 threads cover 4x64
        sidx[c][t] = srcI[ebase0 + c * 64 + t];
        didx[c][t] = dstI[ebase0 + c * 64 + t];
    }

    short8 wf[2][4];
    load_wfrag(W + (size_t)(2 + vr) * D_DIM * D_DIM, w, l15, lq, wf);
    float bias[2];
#pragma unroll
    for (int n = 0; n < 2; ++n)
        bias[n] = b[(size_t)(2 + vr) * D_DIM + (w * 2 + n) * 16 + l15];

    const int srow = tid >> 5;            // staging: 32 thr/row, 16B each
    const int sf4  = tid & 31;
    __syncthreads();                      // sidx visible

    // prefetch + stage chunk 0
    float4 st[8];
#pragma unroll
    for (int it = 0; it < 8; ++it) {
        int row = it * 8 + srow;
        st[it] = *reinterpret_cast<const float4*>(
                     x + (size_t)sidx[0][row] * D_DIM + sf4 * 4);
    }
#pragma unroll
    for (int it = 0; it < 8; ++it) {
        int row = it * 8 + srow;
        unsigned lo = (unsigned)f2bf(st[it].x) | ((unsigned)f2bf(st[it].y) << 16);
        unsigned hi = (unsigned)f2bf(st[it].z) | ((unsigned)f2bf(st[it].w) << 16);
        unsigned byte = ((unsigned)(row * 256 + sf4 * 8))
                      ^ (((unsigned)(row & 7)) << 4);
        *reinterpret_cast<uint2*>(reinterpret_cast<char*>(xs) + byte) =
            make_uint2(lo, hi);
    }
    __syncthreads();

    for (int ch = 0; ch < CPB; ++ch) {
        // issue next chunk's gather early (hides under mfma+transpose)
        float4 nx[8];
        if (ch + 1 < CPB) {
#pragma unroll
            for (int it = 0; it < 8; ++it) {
                int row = it * 8 + srow;
                nx[it] = *reinterpret_cast<const float4*>(
                             x + (size_t)sidx[ch + 1][row] * D_DIM + sf4 * 4);
            }
        }

        f32x4 acc[4][2];
#pragma unroll
        for (int m = 0; m < 4; ++m)
#pragma unroll
            for (int n = 0; n < 2; ++n) acc[m][n] = (f32x4){0.f, 0.f, 0.f, 0.f};
        mfma_tile(xs, wf, l15, lq, acc);

        // reserve dst-sorted slots: ONE int atomic per edge
        if (tid < 64) pos[tid] = atomicAdd(&cur[didx[ch][tid]], 1);

        // transpose acc (+bias) -> bf16 tr tile
#pragma unroll
        for (int m = 0; m < 4; ++m)
#pragma unroll
            for (int reg = 0; reg < 4; ++reg) {
                int row = m * 16 + lq * 4 + reg;
#pragma unroll
                for (int n = 0; n < 2; ++n)
                    tr[row * MSG_LDW + w * 32 + n * 16 + l15] =
                        f2bf(acc[m][n][reg] + bias[n]);
            }
        __syncthreads();   // tr + pos ready; xs fully consumed

        // store msg rows (256B contiguous per instr); write next chunk to xs
#pragma unroll
        for (int i = 0; i < 16; ++i) {
            int r0 = w * 16 + i;
            unsigned dw = *reinterpret_cast<const unsigned*>(
                              reinterpret_cast<const char*>(tr)
                              + r0 * MSG_LDW * 2 + lane * 4);
            msg[(size_t)pos[r0] * 64 + lane] = dw;
        }
        if (ch + 1 < CPB) {
#pragma unroll
            for (int it = 0; it < 8; ++it) {
                int row = it * 8 + srow;
                unsigned lo = (unsigned)f2bf(nx[it].x) | ((unsigned)f2bf(nx[it].y) << 16);
                unsigned hi = (unsigned)f2bf(nx[it].z) | ((unsigned)f2bf(nx[it].w) << 16);
                unsigned byte = ((unsigned)(row * 256 + sf4 * 8))
                              ^ (((unsigned)(row & 7)) << 4);
                *reinterpret_cast<uint2*>(reinterpret_cast<char*>(xs) + byte) =
                    make_uint2(lo, hi);
            }
            __syncthreads();   // xs ready for next mfma; tr free
        }
    }
}

// ====== fused: self-GEMM + monotone streaming msg reduce + bias + ReLU =====
// Self tile stored as bf16 (unioned with xs) -> 17KB LDS.
// Tail-free clamped 16-deep stream; msgs accumulate in f32 registers.
__global__ __launch_bounds__(256) void agg_kernel(const float* __restrict__ x,
                                                  const float* __restrict__ W,
                                                  const float* __restrict__ b,
                                                  const int* __restrict__ off,
                                                  const int* __restrict__ deg,
                                                  const unsigned* __restrict__ msg,
                                                  float* __restrict__ out) {
    // union: xs (16KB) -> self tile bf16 (64 x MSG_LDW, 16.9KB)
    __shared__ __align__(16) char smem[64 * MSG_LDW * 2];
    unsigned short* xs = (unsigned short*)smem;
    unsigned short* st = (unsigned short*)smem;
    __shared__ int offs[64 + 1];   // offs[64] = end of block's row range

    const int tid = threadIdx.x;
    const int lane = tid & 63, w = tid >> 6;
    const int l15 = lane & 15, lq = lane >> 4;
    const int base = blockIdx.x * 64;

    if (tid < 64) offs[tid] = off[base + tid];
    if (tid == 64) offs[64] = off[base + 63] + deg[base + 63];

    short8 wf[2][4];
    load_wfrag(W, w, l15, lq, wf);          // W[SELF]
    float bias[2];
#pragma unroll
    for (int n = 0; n < 2; ++n) bias[n] = b[(w * 2 + n) * 16 + l15];

    // stage 64 consecutive node rows
#pragma unroll
    for (int it = 0; it < 8; ++it) {
        int flat = it * 256 + tid;
        int row = flat >> 5, f4 = flat & 31;
        float4 v = *reinterpret_cast<const float4*>(
                       x + (size_t)(base + row) * D_DIM + f4 * 4);
        unsigned lo = (unsigned)f2bf(v.x) | ((unsigned)f2bf(v.y) << 16);
        unsigned hi = (unsigned)f2bf(v.z) | ((unsigned)f2bf(v.w) << 16);
        unsigned byte = ((unsigned)(row * 256 + f4 * 8))
                      ^ (((unsigned)(row & 7)) << 4);
        *reinterpret_cast<uint2*>(reinterpret_cast<char*>(xs) + byte) =
            make_uint2(lo, hi);
    }
    __syncthreads();

    f32x4 acc[4][2];
#pragma unroll
    for (int m = 0; m < 4; ++m)
#pragma unroll
        for (int n = 0; n < 2; ++n) acc[m][n] = (f32x4){0.f, 0.f, 0.f, 0.f};
    mfma_tile(xs, wf, l15, lq, acc);
    __syncthreads();   // xs consumed; LDS becomes bf16 self tile

    // seed self tile with self-term (+bias), bf16
#pragma unroll
    for (int m = 0; m < 4; ++m)
#pragma unroll
        for (int reg = 0; reg < 4; ++reg) {
            int row = m * 16 + lq * 4 + reg;
#pragma unroll
            for (int n = 0; n < 2; ++n)
                st[row * MSG_LDW + w * 32 + n * 16 + l15] =
                    f2bf(acc[m][n][reg] + bias[n]);
        }
    __syncthreads();

    // ---- monotone stream over this wave's contiguous rows ----
    const int nfirst = w * 16;
    int ci = 0;                      // node cursor within wave's 16
    float2 accm = make_float2(0.f, 0.f);

#define FLUSH_NODE()                                                          \
    do {                                                                      \
        const unsigned sv = *reinterpret_cast<const unsigned*>(               \
            reinterpret_cast<const char*>(st)                                 \
            + (nfirst + ci) * MSG_LDW * 2 + lane * 4);                        \
        float2 so;                                                            \
        so.x = fmaxf(bf_lo(sv) + accm.x, 0.f);                                \
        so.y = fmaxf(bf_hi(sv) + accm.y, 0.f);                                \
        *reinterpret_cast<float2*>(                                           \
            out + (size_t)(base + nfirst + ci) * D_DIM + lane * 2) = so;      \
        accm.x = 0.f; accm.y = 0.f;                                           \
        ++ci;                                                                 \
    } while (0)

    const int s0 = offs[nfirst];
    const int s1 = offs[nfirst + 16];
    int nb = offs[nfirst + 1];

    // tail-free: 16 rows in flight, indices clamped to s1-1 (wave-uniform
    // guard j+k<s1 discards overshoot; loads stay in-bounds)
    for (int j = s0; j < s1; j += 16) {
        unsigned v[16];
#pragma unroll
        for (int k = 0; k < 16; ++k) {
            int jj = j + k;
            jj = (jj < s1) ? jj : (s1 - 1);
            v[k] = msg[(size_t)jj * 64 + lane];
        }
#pragma unroll
        for (int k = 0; k < 16; ++k) {
            int jj = j + k;
            if (jj < s1) {
                while (jj >= nb) { FLUSH_NODE(); nb = offs[nfirst + ci + 1]; }
                accm.x += bf_lo(v[k]); accm.y += bf_hi(v[k]);
            }
        }
    }
    // drain remaining nodes (incl. zero-degree tail)
    while (ci < 16) FLUSH_NODE();
#undef FLUSH_NODE
}

// ===================== fallback (R2 atomic path) ===========================
__global__ __launch_bounds__(256) void self_kernel(const float* __restrict__ x,
                                                   const float* __restrict__ W,
                                                   const float* __restrict__ b,
                                                   float* __restrict__ out) {
    __shared__ unsigned short xs[64 * D_DIM];
    const int tid = threadIdx.x;
    const int lane = tid & 63, w = tid >> 6;
    const int l15 = lane & 15, lq = lane >> 4;
    short8 wf[2][4];
    load_wfrag(W, w, l15, lq, wf);
    float bias[2];
#pragma unroll
    for (int n = 0; n < 2; ++n) bias[n] = b[(w * 2 + n) * 16 + l15];
    const int rbase = blockIdx.x * 64;
#pragma unroll
    for (int it = 0; it < 8; ++it) {
        int flat = it * 256 + tid;
        int row = flat >> 5, f4 = flat & 31;
        float4 v = *reinterpret_cast<const float4*>(
                       x + (size_t)(rbase + row) * D_DIM + f4 * 4);
        unsigned lo = (unsigned)f2bf(v.x) | ((unsigned)f2bf(v.y) << 16);
        unsigned hi = (unsigned)f2bf(v.z) | ((unsigned)f2bf(v.w) << 16);
        unsigned byte = ((unsigned)(row * 256 + f4 * 8))
                      ^ (((unsigned)(row & 7)) << 4);
        *reinterpret_cast<uint2*>(reinterpret_cast<char*>(xs) + byte) =
            make_uint2(lo, hi);
    }
    __syncthreads();
    f32x4 acc[4][2];
#pragma unroll
    for (int m = 0; m < 4; ++m)
#pragma unroll
        for (int n = 0; n < 2; ++n) acc[m][n] = (f32x4){0.f, 0.f, 0.f, 0.f};
    mfma_tile(xs, wf, l15, lq, acc);
#pragma unroll
    for (int m = 0; m < 4; ++m)
#pragma unroll
        for (int reg = 0; reg < 4; ++reg) {
            int row = rbase + m * 16 + lq * 4 + reg;
#pragma unroll
            for (int n = 0; n < 2; ++n) {
                int c = (w * 2 + n) * 16 + l15;
                out[(size_t)row * D_DIM + c] = acc[m][n][reg] + bias[n];
            }
        }
}

__global__ __launch_bounds__(256) void edge_kernel(const float* __restrict__ x,
                                                   const float* __restrict__ W,
                                                   const float* __restrict__ b,
                                                   const int* __restrict__ dep,
                                                   const int* __restrict__ gov,
                                                   float* __restrict__ out,
                                                   int eg, int blocksPerRel) {
    __shared__ unsigned short xs[64 * D_DIM];
    __shared__ int sidx[CPB][64];
    __shared__ int didx[CPB][64];
    const int tid = threadIdx.x;
    const int lane = tid & 63, w = tid >> 6;
    const int l15 = lane & 15, lq = lane >> 4;
    const int bid = blockIdx.x;
    const int vr = bid / blocksPerRel;
    const int blk = bid % blocksPerRel;
    const int r = vr & 31;
    const bool fwd = (vr < 32);
    const int* __restrict__ srcI = fwd ? gov : dep;
    const int* __restrict__ dstI = fwd ? dep : gov;
    const int ebase0 = r * eg + blk * CPB * 64;
#pragma unroll
    for (int c2 = 0; c2 < CPB / 4; ++c2) {
        int c = c2 * 4 + (tid >> 6), t = tid & 63;
        sidx[c][t] = srcI[ebase0 + c * 64 + t];
        didx[c][t] = dstI[ebase0 + c * 64 + t];
    }
    short8 wf[2][4];
    load_wfrag(W + (size_t)(2 + vr) * D_DIM * D_DIM, w, l15, lq, wf);
    float bias[2];
#pragma unroll
    for (int n = 0; n < 2; ++n)
        bias[n] = b[(size_t)(2 + vr) * D_DIM + (w * 2 + n) * 16 + l15];
    __syncthreads();
    for (int ch = 0; ch < CPB; ++ch) {
#pragma unroll
        for (int it = 0; it < 8; ++it) {
            int flat = it * 256 + tid;
            int row = flat >> 5, f4 = flat & 31;
            float4 v = *reinterpret_cast<const float4*>(
                           x + (size_t)sidx[ch][row] * D_DIM + f4 * 4);
            unsigned lo = (unsigned)f2bf(v.x) | ((unsigned)f2bf(v.y) << 16);
            unsigned hi = (unsigned)f2bf(v.z) | ((unsigned)f2bf(v.w) << 16);
            unsigned byte = ((unsigned)(row * 256 + f4 * 8))
                          ^ (((unsigned)(row & 7)) << 4);
            *reinterpret_cast<uint2*>(reinterpret_cast<char*>(xs) + byte) =
                make_uint2(lo, hi);
        }
        __syncthreads();
        f32x4 acc[4][2];
#pragma unroll
        for (int m = 0; m < 4; ++m)
#pragma unroll
            for (int n = 0; n < 2; ++n) acc[m][n] = (f32x4){0.f, 0.f, 0.f, 0.f};
        mfma_tile(xs, wf, l15, lq, acc);
#pragma unroll
        for (int m = 0; m < 4; ++m)
#pragma unroll
            for (int reg = 0; reg < 4; ++reg) {
                int erow = m * 16 + lq * 4 + reg;
                int dst = didx[ch][erow];
#pragma unroll
                for (int n = 0; n < 2; ++n) {
                    int c = (w * 2 + n) * 16 + l15;
                    unsafeAtomicAdd(&out[(size_t)dst * D_DIM + c],
                                    acc[m][n][reg] + bias[n]);
                }
            }
        __syncthreads();
    }
}

__global__ void relu_kernel(float* __restrict__ o, int n4) {
    int i = blockIdx.x * blockDim.x + threadIdx.x;
    int stride = gridDim.x * blockDim.x;
    float4* p = reinterpret_cast<float4*>(o);
    for (; i < n4; i += stride) {
        float4 v = p[i];
        v.x = fmaxf(v.x, 0.f); v.y = fmaxf(v.y, 0.f);
        v.z = fmaxf(v.z, 0.f); v.w = fmaxf(v.w, 0.f);
        p[i] = v;
    }
}

// ===========================================================================
extern "C" void kernel_launch(void* const* d_in, const int* in_sizes, int n_in,
                              void* d_out, int out_size, void* d_ws, size_t ws_size,
                              hipStream_t stream) {
    const float* x   = (const float*)d_in[0];
    const float* W   = (const float*)d_in[1];
    const float* b   = (const float*)d_in[2];
    const int*   dep = (const int*)d_in[3];
    const int*   gov = (const int*)d_in[4];
    float* out = (float*)d_out;

    const int N  = in_sizes[0] / D_DIM;   // 262144
    const int E  = in_sizes[3];           // 262144
    const int eg = E / L_REL;             // 8192

    const size_t msgBytes = (size_t)2 * E * 64 * sizeof(unsigned);  // 134.2 MB
    const size_t need = msgBytes + (size_t)(3 * N + 256) * 4 + 4096;

    const int blocksPerRel = eg / 64 / CPB;   // 16 -> grid 1024 = 4 blocks/CU

    if (ws_size >= need) {
        char* basep = (char*)d_ws;
        unsigned* msg = (unsigned*)basep;
        int* deg = (int*)(basep + msgBytes);   // [N]
        int* off = deg + (size_t)N;            // [N]
        int* cur = off + (size_t)N;            // [N]
        int* partials = cur + (size_t)N;       // [256]

        hipMemsetAsync(deg, 0, (size_t)N * sizeof(int), stream);
        hist_kernel<<<1024, 256, 0, stream>>>(dep, gov, deg, E);
        scanA_kernel<<<N / 1024, 256, 0, stream>>>(deg, off, partials);
        scanB_kernel<<<1, 256, 0, stream>>>(partials);
        scanC_kernel<<<N / 1024, 256, 0, stream>>>(off, cur, partials);

        msg_kernel<<<64 * blocksPerRel, 256, 0, stream>>>(x, W, b, dep, gov,
                                                          cur, msg, eg,
                                                          blocksPerRel);
        agg_kernel<<<N / 64, 256, 0, stream>>>(x, W, b, off, deg, msg, out);
    } else {
        // fallback: atomic scatter path
        self_kernel<<<N / 64, 256, 0, stream>>>(x, W, b, out);
        edge_kernel<<<64 * blocksPerRel, 256, 0, stream>>>(x, W, b, dep, gov, out,
                                                           eg, blocksPerRel);
        relu_kernel<<<2048, 256, 0, stream>>>(out, out_size / 4);
    }
}